// Round 15
// baseline (1138.110 us; speedup 1.0000x reference)
//
#include <hip/hip_runtime.h>
#include <cmath>

// fusion_36455682409119 round 15: r14 base (1107us) + launch-shape fixes.
//  - om conv: ONE z=16 dispatch per pack (NM=4, chunk-3 zero-padded; store path
//    guards ocg<216). Kills 23%-fill z=4 tail launches; main fill 58%->94%.
//  - tacorr: TH=2 (dual halo 2x17.4KB, 4 blk/CU, 3600 blocks = 88% fill).
//  - mdcn: CLOSED at vector-request-rate roofline (66.4M lines @ 1 req/cyc/CU
//    = 193us, measured == model within 1%).

using short8 = __attribute__((ext_vector_type(8))) short;
using f32x4  = __attribute__((ext_vector_type(4))) float;
using f32x2  = __attribute__((ext_vector_type(2))) float;

#define DEVINL static __device__ __forceinline__

DEVINL unsigned short f2bf(float f){
    unsigned u = __float_as_uint(f);
    u += 0x7fffu + ((u >> 16) & 1u);
    return (unsigned short)(u >> 16);
}
DEVINL unsigned pack2(float a, float b){ return (unsigned)f2bf(a) | ((unsigned)f2bf(b) << 16); }
DEVINL float bflo(unsigned u){ return __uint_as_float(u << 16); }
DEVINL float bfhi(unsigned u){ return __uint_as_float(u & 0xffff0000u); }
DEVINL float bf2f(unsigned short u){ return __uint_as_float((unsigned)u << 16); }
DEVINL float lrelu_f(float v){ return v >= 0.f ? v : 0.1f * v; }
DEVINL f32x2 up2(unsigned u){
    return f32x2{__uint_as_float(u << 16), __uint_as_float(u & 0xffff0000u)};
}

// m204 bijective XCD swizzle
DEVINL void swz_decode(int& bx, int& by, int& bz){
    const int gx = gridDim.x, gy = gridDim.y;
    int lin = blockIdx.x + gx * (blockIdx.y + gy * blockIdx.z);
    int nwg = gx * gy * gridDim.z;
    int q = nwg >> 3, r = nwg & 7;
    int xcd = lin & 7, idx = lin >> 3;
    int swz = (xcd < r ? xcd * (q + 1) : r + xcd * q) + idx;
    bz = swz / (gx * gy);
    int rem = swz - bz * gx * gy;
    by = rem / gx; bx = rem - by * gx;
}

struct Ptr4 { unsigned short* p[4]; };

// ---------------- both NCHW f32 -> NHWC bf16 transposes in one launch ----------------
__global__ __launch_bounds__(256) void nchw2nhwc2(const float* __restrict__ inA,
                                                  const float* __restrict__ inB,
                                                  unsigned short* __restrict__ outA,
                                                  unsigned short* __restrict__ outB)
{
    constexpr int HW = 180 * 320;
    const int blk = blockIdx.x;
    const float* in = (blk < 900) ? inA : inB;
    unsigned short* out = (blk < 900) ? outA : outB;
    size_t idx = (size_t)(blk % 900) * 256 + threadIdx.x;
    size_t bb = idx / HW, p = idx % HW;
    const float* src = in + (bb * 64) * (size_t)HW + p;
    unsigned short* dst = out + idx * 64;
    #pragma unroll
    for (int c0 = 0; c0 < 64; c0 += 16) {
        unsigned r[8];
        #pragma unroll
        for (int q = 0; q < 8; ++q)
            r[q] = pack2(src[(size_t)(c0 + 2*q) * HW], src[(size_t)(c0 + 2*q + 1) * HW]);
        *(uint4*)(dst + c0)     = *(uint4*)&r[0];
        *(uint4*)(dst + c0 + 8) = *(uint4*)&r[4];
    }
}

// ---------------- all weight prepacks in one launch ----------------
// kind 0: conv order [ch][j][cs][64oc][32k], k=c (oc >= cout zero-padded).
// kind 1: mdcn GROUP-major [s(18)][64oc][32k], k_lin = (g*9+tap)*8+c
struct PrepArgs {
    const float* src[11];
    unsigned short* dst[11];
    int cout[11]; int cin[11]; int nch[11]; int kind[11];
};

__global__ __launch_bounds__(256) void prep_all(PrepArgs a)
{
    const int t = blockIdx.y;
    const int idx = blockIdx.x * 256 + threadIdx.x;
    if (a.kind[t] == 1) {
        if (idx >= 36864) return;
        int kk = idx & 31, oc = (idx >> 5) & 63, s = idx >> 11;
        int k = s * 32 + kk;
        int gt = k >> 3, c8 = k & 7;
        int g = gt / 9, tp = gt - g * 9;
        a.dst[t][idx] = f2bf(a.src[t][((size_t)oc * 64 + g * 8 + c8) * 9 + tp]);
    } else {
        int cin = a.cin[t], cout = a.cout[t];
        int ncs = cin / 32;
        int total = a.nch[t] * 9 * ncs * 2048;
        if (idx >= total) return;
        int kk = idx & 31, oc_l = (idx >> 5) & 63, rest = idx >> 11;
        int cs = rest % ncs; int rest2 = rest / ncs;
        int j = rest2 % 9; int ch = rest2 / 9;
        int oc = ch * 64 + oc_l, c = cs * 32 + kk;
        float v = (oc < cout) ? a.src[t][((size_t)oc * cin + c) * 9 + j] : 0.f;
        a.dst[t][idx] = f2bf(v);
    }
}

// ---------------- MFMA conv 3x3 SAME, 64oc-chunk x (TH rows x 64px), HALVES passes ----
// TH=4: wave=row, 4 n-frags/wave (om path). TH=2: wave=(row,xhalf), 2 frags.
// OUTMODE 0: bf16 NHWC. 1: bf16 PLANAR via omout.p[b] (TH=4 only). 2: f32 NCHW +res.
template<bool ACT, bool SCALE, int OUTMODE, int NM, int HALVES, int TH>
__global__ __launch_bounds__(256, (TH == 2 ? 4 : 3)) void conv_mfma(
    const unsigned short* __restrict__ in0, const unsigned short* __restrict__ in1,
    const unsigned short* __restrict__ wgt, const float* __restrict__ bias,
    unsigned short* __restrict__ out, const float* __restrict__ corr,
    const float* __restrict__ res, float* __restrict__ outf,
    Ptr4 omout, int choff, int zdiv)
{
    constexpr int H = 180, W = 320, HW = H * W;
    constexpr int XW = 66;
    constexpr int HR = TH + 2;
    constexpr int NE = HR * XW * 8;
    constexpr int NFW = (TH == 4) ? 4 : 2;
    __shared__ __align__(16) unsigned char lds[HR * XW * 64 * 2];

    const int tid = threadIdx.x;
    int bx, by, bz;
    swz_decode(bx, by, bz);
    int b, ch;
    if (OUTMODE == 1) { b = bz / zdiv; ch = bz % zdiv + choff; }
    else              { b = bz; ch = 0; }
    const int x0 = bx * 64, y0 = by * TH;

    const int wv = tid >> 6, lane = tid & 63;
    const int ll = lane & 15, lh = lane >> 4;
    const int row_w = (TH == 4) ? wv : (wv & 1);
    const int nf0   = (TH == 4) ? 0  : ((wv >> 1) * 2);
    const unsigned short* wchunk = wgt + (size_t)ch * (9 * 2 * 2048);
    const int alane = ll * 32 + lh * 8;

    f32x4 acc[NM][NFW];
    #pragma unroll
    for (int mi = 0; mi < NM; ++mi)
        #pragma unroll
        for (int nf = 0; nf < NFW; ++nf) acc[mi][nf] = f32x4{0.f, 0.f, 0.f, 0.f};

    #pragma unroll
    for (int h = 0; h < HALVES; ++h) {
        if (h) __syncthreads();
        const unsigned short* srcb = (HALVES == 2 && h == 1) ? in1 : in0;
        for (int t = tid; t < NE; t += 256) {
            int cb = t & 7; int r = t >> 3;
            int xp = r % XW, yp = r / XW;
            int gx = x0 - 1 + xp, gy = y0 - 1 + yp;
            uint4 v = make_uint4(0, 0, 0, 0);
            if (gx >= 0 && gx < W && gy >= 0 && gy < H) {
                size_t pix = (size_t)b * HW + (size_t)gy * W + gx;
                v = *(const uint4*)(srcb + pix * 64 + cb * 8);
                if (SCALE) {
                    float cv = corr[pix];
                    v.x = pack2(bflo(v.x) * cv, bfhi(v.x) * cv);
                    v.y = pack2(bflo(v.y) * cv, bfhi(v.y) * cv);
                    v.z = pack2(bflo(v.z) * cv, bfhi(v.z) * cv);
                    v.w = pack2(bflo(v.w) * cv, bfhi(v.w) * cv);
                }
            }
            int blk = cb ^ (xp & 7);
            *(uint4*)&lds[(size_t)((yp * XW + xp) * 8 + blk) * 16] = v;
        }
        __syncthreads();

        #pragma unroll
        for (int j = 0; j < 9; ++j) {
            const int jy = j / 3, jx = j % 3;
            #pragma unroll
            for (int csl = 0; csl < 2; ++csl) {
                const int ws = j * (2 * HALVES) + h * 2 + csl;
                short8 a[NM];
                #pragma unroll
                for (int mi = 0; mi < NM; ++mi)
                    a[mi] = *(const short8*)(wchunk + (size_t)ws * 2048 + mi * 512 + alane);
                short8 bf[NFW];
                #pragma unroll
                for (int nfl = 0; nfl < NFW; ++nfl) {
                    int xp = (nf0 + nfl) * 16 + ll + jx;
                    int blk = (csl * 4 + lh) ^ (xp & 7);
                    int addr = (((row_w + jy) * XW + xp) * 8 + blk) * 16;
                    bf[nfl] = *(const short8*)&lds[addr];
                }
                #pragma unroll
                for (int mi = 0; mi < NM; ++mi)
                    #pragma unroll
                    for (int nfl = 0; nfl < NFW; ++nfl)
                        acc[mi][nfl] = __builtin_amdgcn_mfma_f32_16x16x32_bf16(a[mi], bf[nfl], acc[mi][nfl], 0, 0, 0);
            }
        }
    }

    const int py = y0 + row_w;
    const size_t pixrow = (size_t)b * HW + (size_t)py * W;

    if (OUTMODE == 1) {
        if constexpr (TH == 4) {
            // transpose via LDS (stride 72 px, 2B): full 128B-line planar stores
            __syncthreads();
            unsigned short* t2 = (unsigned short*)lds;
            #pragma unroll
            for (int nfl = 0; nfl < NFW; ++nfl) {
                const int px = nfl * 16 + ll;
                #pragma unroll
                for (int mi = 0; mi < NM; ++mi) {
                    #pragma unroll
                    for (int jj = 0; jj < 4; ++jj) {
                        int oc = mi * 16 + lh * 4 + jj;
                        int ocg = ch * 64 + oc;
                        if (ocg < 216) {
                            float t = acc[mi][nfl][jj] + bias[ocg];
                            t2[(size_t)(wv * 64 + oc) * 72 + px] = f2bf(ACT ? lrelu_f(t) : t);
                        }
                    }
                }
            }
            __syncthreads();
            unsigned short* oslot = omout.p[b];
            #pragma unroll
            for (int i = 0; i < 8; ++i) {
                int gu = i * 32 + (tid >> 3), q = tid & 7;
                int row = gu >> 6, oc = gu & 63;
                int ocg = ch * 64 + oc;
                if (oc < NM * 16 && ocg < 216) {
                    uint4 v = *(uint4*)&t2[(size_t)(row * 64 + oc) * 72 + q * 8];
                    *(uint4*)&oslot[(size_t)ocg * HW + (size_t)(y0 + row) * W + x0 + q * 8] = v;
                }
            }
        }
        return;
    }

    #pragma unroll
    for (int nfl = 0; nfl < NFW; ++nfl) {
        const int px = x0 + (nf0 + nfl) * 16 + ll;
        #pragma unroll
        for (int mi = 0; mi < NM; ++mi) {
            const int oc_l = mi * 16 + lh * 4;
            if (OUTMODE == 0) {
                float v[4];
                #pragma unroll
                for (int jj = 0; jj < 4; ++jj) {
                    float t = acc[mi][nfl][jj] + bias[oc_l + jj];
                    v[jj] = ACT ? lrelu_f(t) : t;
                }
                uint2 st; st.x = pack2(v[0], v[1]); st.y = pack2(v[2], v[3]);
                *(uint2*)&out[(pixrow + px) * 64 + oc_l] = st;
            } else {
                #pragma unroll
                for (int jj = 0; jj < 4; ++jj) {
                    int oc = oc_l + jj;
                    float t = acc[mi][nfl][jj] + bias[oc];
                    if (ACT) t = lrelu_f(t);
                    size_t idx = ((size_t)b * 64 + oc) * HW + (size_t)py * W + px;
                    outf[idx] = t + res[idx];
                }
            }
        }
    }
}

// ---------------- fused ta1+ta2+corr, TH=2 (dual halo 2x17.4KB, 4 blk/CU) ----------------
__global__ __launch_bounds__(256, 4) void tacorr_mfma(
    const unsigned short* __restrict__ inR,
    const unsigned short* __restrict__ inE,
    const unsigned short* __restrict__ wR, const float* __restrict__ bR,
    const unsigned short* __restrict__ wE, const float* __restrict__ bE,
    float* __restrict__ outf)
{
    constexpr int H = 180, W = 320, HW = H * W;
    constexpr int NE1 = 4 * 34 * 8;   // 1088 slots per half
    __shared__ __align__(16) unsigned char lds[2][4 * 34 * 64 * 2];

    const int tid = threadIdx.x;
    int bx, by, bz;
    swz_decode(bx, by, bz);
    const int b = bz;
    const int x0 = bx * 32, y0 = by * 2;

    for (int t = tid; t < 2 * NE1; t += 256) {
        int half = t / NE1, e = t - half * NE1;
        int cb = e & 7; int r = e >> 3;
        int xp = r % 34, yp = r / 34;
        int gx = x0 - 1 + xp, gy = y0 - 1 + yp;
        uint4 v = make_uint4(0, 0, 0, 0);
        if (gx >= 0 && gx < W && gy >= 0 && gy < H) {
            size_t pix = (size_t)b * HW + (size_t)gy * W + gx;
            const unsigned short* src = (half ? inE : inR) + pix * 64 + cb * 8;
            v = *(const uint4*)src;
        }
        int blk = cb ^ (xp & 7);
        *(uint4*)&lds[half][(size_t)((yp * 34 + xp) * 8 + blk) * 16] = v;
    }
    __syncthreads();

    const int wv = tid >> 6, lane = tid & 63;
    const int ll = lane & 15, lh = lane >> 4;
    const int row_w = wv & 1, nfw = wv >> 1;   // wave = (row, x-half)
    const int alane = ll * 32 + lh * 8;

    f32x4 accR[4], accE[4];
    #pragma unroll
    for (int mi = 0; mi < 4; ++mi) { accR[mi] = f32x4{0,0,0,0}; accE[mi] = f32x4{0,0,0,0}; }

    #pragma unroll
    for (int j = 0; j < 9; ++j) {
        const int jy = j / 3, jx = j % 3;
        #pragma unroll
        for (int cs = 0; cs < 2; ++cs) {
            const int s = j * 2 + cs;
            short8 aR[4], aE[4];
            #pragma unroll
            for (int mi = 0; mi < 4; ++mi) {
                aR[mi] = *(const short8*)(wR + (size_t)s * 2048 + mi * 512 + alane);
                aE[mi] = *(const short8*)(wE + (size_t)s * 2048 + mi * 512 + alane);
            }
            int xp = nfw * 16 + ll + jx;
            int blk = (cs * 4 + lh) ^ (xp & 7);
            int addr = (((row_w + jy) * 34 + xp) * 8 + blk) * 16;
            short8 bfR = *(const short8*)&lds[0][addr];
            short8 bfE = *(const short8*)&lds[1][addr];
            #pragma unroll
            for (int mi = 0; mi < 4; ++mi) {
                accR[mi] = __builtin_amdgcn_mfma_f32_16x16x32_bf16(aR[mi], bfR, accR[mi], 0, 0, 0);
                accE[mi] = __builtin_amdgcn_mfma_f32_16x16x32_bf16(aE[mi], bfE, accE[mi], 0, 0, 0);
            }
        }
    }

    const int py = y0 + row_w;
    const size_t pixrow = (size_t)b * HW + (size_t)py * W;
    const int px = x0 + nfw * 16 + ll;
    float dot = 0.f;
    #pragma unroll
    for (int mi = 0; mi < 4; ++mi) {
        const int oc_l = mi * 16 + lh * 4;
        #pragma unroll
        for (int jj = 0; jj < 4; ++jj)
            dot += (accR[mi][jj] + bR[oc_l + jj]) * (accE[mi][jj] + bE[oc_l + jj]);
    }
    dot += __shfl_xor(dot, 16);
    dot += __shfl_xor(dot, 32);
    if (lh == 0) outf[pixrow + px] = dot;
}

// ---------------- mdcn (request-rate roofline): group-major, single-phase ----------------
template<int ACT>
__global__ __launch_bounds__(256, 4) void mdcn_mfma(
    const unsigned short* __restrict__ x, Ptr4 omslots,
    const unsigned short* __restrict__ wgt, const float* __restrict__ bias,
    unsigned short* __restrict__ out)
{
    constexpr int H = 180, W = 320, HW = H * W;
    constexpr size_t CHW = (size_t)HW * 64;
    __shared__ __align__(16) unsigned char sv[72 * 32 * 16];

    const int tid = threadIdx.x;
    int bx, by, bz;
    swz_decode(bx, by, bz);
    const unsigned short* xb  = x + (size_t)bz * CHW;
    const unsigned short* omb = omslots.p[bz];
    unsigned short* ob        = out + (size_t)bz * CHW;
    const int px0 = bx * 32;
    const int py  = by;

    {
        const int pxl = tid & 31, g = tid >> 5;
        const int px = px0 + pxl;
        const size_t p = (size_t)py * W + px;
        const unsigned short* omg = omb + (size_t)(g * 9) * HW + p;

        float oyv[9], oxv[9], mmv[9];
        #pragma unroll
        for (int k = 0; k < 9; ++k) oyv[k] = bf2f(omg[(size_t)k * HW]);
        #pragma unroll
        for (int k = 0; k < 9; ++k) oxv[k] = bf2f(omg[(size_t)(72 + k) * HW]);
        #pragma unroll
        for (int k = 0; k < 9; ++k) mmv[k] = bf2f(omg[(size_t)(144 + k) * HW]);

        #pragma unroll
        for (int k = 0; k < 9; ++k) {
            float m = 1.f / (1.f + __expf(-mmv[k]));
            float pyf = (float)(py + (k / 3) - 1) + oyv[k];
            float pxf = (float)(px + (k % 3) - 1) + oxv[k];
            float y0f = floorf(pyf), x0f = floorf(pxf);
            float wy = pyf - y0f, wx = pxf - x0f;
            int yi = (int)y0f, xi = (int)x0f;
            bool vy0 = (yi >= 0) && (yi < H);
            bool vy1 = (yi + 1 >= 0) && (yi + 1 < H);
            bool vx0 = (xi >= 0) && (xi < W);
            bool vx1 = (xi + 1 >= 0) && (xi + 1 < W);
            float w00 = (vy0 && vx0) ? (1.f - wy) * (1.f - wx) * m : 0.f;
            float w01 = (vy0 && vx1) ? (1.f - wy) * wx * m : 0.f;
            float w10 = (vy1 && vx0) ? wy * (1.f - wx) * m : 0.f;
            float w11 = (vy1 && vx1) ? wy * wx * m : 0.f;
            int yc0 = min(max(yi, 0), H - 1), yc1 = min(max(yi + 1, 0), H - 1);
            int xc0 = min(max(xi, 0), W - 1), xc1 = min(max(xi + 1, 0), W - 1);
            uint4 c00 = *(const uint4*)(xb + ((size_t)(yc0 * W + xc0) * 64 + g * 8));
            uint4 c01 = *(const uint4*)(xb + ((size_t)(yc0 * W + xc1) * 64 + g * 8));
            uint4 c10 = *(const uint4*)(xb + ((size_t)(yc1 * W + xc0) * 64 + g * 8));
            uint4 c11 = *(const uint4*)(xb + ((size_t)(yc1 * W + xc1) * 64 + g * 8));
            const unsigned* p00 = (const unsigned*)&c00;
            const unsigned* p01 = (const unsigned*)&c01;
            const unsigned* p10 = (const unsigned*)&c10;
            const unsigned* p11 = (const unsigned*)&c11;
            unsigned r[4];
            #pragma unroll
            for (int q = 0; q < 4; ++q) {
                f32x2 rv = up2(p00[q]) * w00 + up2(p01[q]) * w01
                         + up2(p10[q]) * w10 + up2(p11[q]) * w11;
                r[q] = pack2(rv[0], rv[1]);
            }
            *(uint4*)&sv[(size_t)((g * 9 + k) * 32 + pxl) * 16] = *(uint4*)r;
        }
    }
    __syncthreads();

    const int wv = tid >> 6, lane = tid & 63;
    const int ll = lane & 15, lh = lane >> 4;
    f32x4 acc[2] = {f32x4{0.f,0.f,0.f,0.f}, f32x4{0.f,0.f,0.f,0.f}};
    #pragma unroll
    for (int s = 0; s < 18; ++s) {
        short8 a = *(const short8*)(wgt + (size_t)(s * 64 + wv * 16 + ll) * 32 + lh * 8);
        #pragma unroll
        for (int nf = 0; nf < 2; ++nf) {
            short8 bb = *(const short8*)&sv[(size_t)s * 2048 + lh * 512 + (nf * 16 + ll) * 16];
            acc[nf] = __builtin_amdgcn_mfma_f32_16x16x32_bf16(a, bb, acc[nf], 0, 0, 0);
        }
    }
    #pragma unroll
    for (int nf = 0; nf < 2; ++nf) {
        int opx = px0 + nf * 16 + ll;
        int oc0 = wv * 16 + lh * 4;
        float v[4];
        #pragma unroll
        for (int jj = 0; jj < 4; ++jj) {
            float t = acc[nf][jj] + bias[oc0 + jj];
            v[jj] = ACT ? lrelu_f(t) : t;
        }
        uint2 st; st.x = pack2(v[0], v[1]); st.y = pack2(v[2], v[3]);
        *(uint2*)&ob[((size_t)py * W + opx) * 64 + oc0] = st;
    }
}

extern "C" void kernel_launch(void* const* d_in, const int* in_sizes, int n_in,
                              void* d_out, int out_size, void* d_ws, size_t ws_size,
                              hipStream_t stream)
{
    const float* ref    = (const float*)d_in[0];
    const float* neb    = (const float*)d_in[1];
    const float* w_oc1  = (const float*)d_in[2];  const float* b_oc1  = (const float*)d_in[3];
    const float* w_om1  = (const float*)d_in[4];  const float* b_om1  = (const float*)d_in[5];
    const float* w_dcn1 = (const float*)d_in[6];  const float* b_dcn1 = (const float*)d_in[7];
    const float* w_fc   = (const float*)d_in[8];  const float* b_fc   = (const float*)d_in[9];
    const float* w_cas1 = (const float*)d_in[10]; const float* b_cas1 = (const float*)d_in[11];
    const float* w_cas2 = (const float*)d_in[12]; const float* b_cas2 = (const float*)d_in[13];
    const float* w_om2  = (const float*)d_in[14]; const float* b_om2  = (const float*)d_in[15];
    const float* w_dcn2 = (const float*)d_in[16]; const float* b_dcn2 = (const float*)d_in[17];
    const float* w_ta1  = (const float*)d_in[18]; const float* b_ta1  = (const float*)d_in[19];
    const float* w_ta2  = (const float*)d_in[20]; const float* b_ta2  = (const float*)d_in[21];
    const float* w_ff   = (const float*)d_in[22]; const float* b_ff   = (const float*)d_in[23];

    constexpr int H = 180, W = 320, HW = H * W;
    constexpr size_t CHW = (size_t)HW * 64;
    constexpr size_t SLB = 4 * CHW * 2;
    constexpr size_t OMSLOT_EL = (size_t)HW * 216;
    constexpr size_t OMSLOT_B  = OMSLOT_EL * 2;

    char* wsb = (char*)d_ws;
    unsigned short* S0 = (unsigned short*)(wsb);
    unsigned short* S1 = (unsigned short*)(wsb + SLB);
    unsigned short* S2 = (unsigned short*)(wsb + 2 * SLB);
    unsigned short* S3 = (unsigned short*)(wsb + 3 * SLB);
    float* corrf = (float*)S3;
    unsigned short* ffw = (unsigned short*)(wsb + SLB + (2u << 20));

    char* doutb = (char*)d_out;
    unsigned short* omA0 = (unsigned short*)doutb;
    unsigned short* omA1 = omA0 + OMSLOT_EL;
    unsigned short* wb   = (unsigned short*)(doutb + 2 * OMSLOT_B);
    const bool big = ws_size >= 4 * SLB + 2 * OMSLOT_B;
    unsigned short* omB0 = (unsigned short*)(wsb + 4 * SLB);
    unsigned short* omB1 = omB0 + OMSLOT_EL;

    unsigned short* w_oc1p = wb + 0;
    unsigned short* w_om1p = wb + 73728;
    unsigned short* w_dcn1p= wb + 221184;
    unsigned short* w_fcp  = wb + 258048;
    unsigned short* w_cas1p= wb + 294912;
    unsigned short* w_cas2p= wb + 368640;
    unsigned short* w_om2p = wb + 405504;
    unsigned short* w_dcn2p= wb + 552960;
    unsigned short* w_ta1p = wb + 589824;
    unsigned short* w_ta2p = wb + 626688;
    unsigned short* w_ffp  = wb + 663552;

    dim3 blk(256);
    dim3 gf(5, 90, 4);        // feature convs: TH=2, 1800 blocks
    dim3 gt(10, 90, 4);       // tacorr: TH=2, 3600 blocks
    Ptr4 none{};

    nchw2nhwc2<<<1800, blk, 0, stream>>>(ref, neb, S0, S1);

    {
        PrepArgs pa;
        const float* srcs[11] = {w_oc1, w_om1, w_dcn1, w_fc, w_cas1, w_cas2, w_om2, w_dcn2, w_ta1, w_ta2, w_ff};
        unsigned short* dsts[11] = {w_oc1p, w_om1p, w_dcn1p, w_fcp, w_cas1p, w_cas2p, w_om2p, w_dcn2p, w_ta1p, w_ta2p, w_ffp};
        int couts[11] = {64, 216, 0, 64, 64, 64, 216, 0, 64, 64, 64};
        int cins[11]  = {128, 64, 0, 64, 128, 64, 64, 0, 64, 64, 64};
        int nchs[11]  = {1, 4, 0, 1, 1, 1, 4, 0, 1, 1, 1};
        int kinds[11] = {0, 0, 1, 0, 0, 0, 0, 1, 0, 0, 0};
        for (int i = 0; i < 11; ++i) {
            pa.src[i] = srcs[i]; pa.dst[i] = dsts[i];
            pa.cout[i] = couts[i]; pa.cin[i] = cins[i]; pa.nch[i] = nchs[i]; pa.kind[i] = kinds[i];
        }
        prep_all<<<dim3(576, 11), blk, 0, stream>>>(pa);
    }

    // 1. off1 = lrelu(conv(concat(neb,ref))) -> S2   (two-half staging, TH=2)
    conv_mfma<true, false, 0, 4, 2, 2><<<gf, blk, 0, stream>>>(
        S1, S0, w_oc1p, b_oc1, S2, nullptr, nullptr, nullptr, none, 0, 1);

    // om conv: SINGLE z=4*nb dispatch, NM=4 (chunk 3 zero-padded), TH=4 epilogue
    auto ompack = [&](const unsigned short* inp, const unsigned short* wp, const float* bp,
                      Ptr4 slots, int nb){
        conv_mfma<false, false, 1, 4, 1, 4><<<dim3(5, 45, 4 * nb), blk, 0, stream>>>(
            inp, nullptr, wp, bp, nullptr, nullptr, nullptr, nullptr, slots, 0, 4);
    };

    // 2. pack1: om1 = conv(off1) [planar]; feat1 = mdcn(neb_t, om1) -> S3
    if (big) {
        Ptr4 slots{omA0, omA1, omB0, omB1};
        ompack(S2, w_om1p, b_om1, slots, 4);
        mdcn_mfma<0><<<dim3(10, 180, 4), blk, 0, stream>>>(S1, slots, w_dcn1p, b_dcn1, S3);
    } else {
        Ptr4 slots{omA0, omA1, nullptr, nullptr};
        for (int pp = 0; pp < 2; ++pp) {
            ompack(S2 + 2 * pp * CHW, w_om1p, b_om1, slots, 2);
            mdcn_mfma<0><<<dim3(10, 180, 2), blk, 0, stream>>>(S1 + 2 * pp * CHW, slots,
                                                               w_dcn1p, b_dcn1, S3 + 2 * pp * CHW);
        }
    }

    // 3. feat2 = lrelu(conv(feat1)) -> S2   (TH=2)
    conv_mfma<true, false, 0, 4, 1, 2><<<gf, blk, 0, stream>>>(
        S3, nullptr, w_fcp, b_fc, S2, nullptr, nullptr, nullptr, none, 0, 1);
    // 4. cas_a = lrelu(conv(concat(feat2,ref))) -> S1   (two-half, TH=2)
    conv_mfma<true, false, 0, 4, 2, 2><<<gf, blk, 0, stream>>>(
        S2, S0, w_cas1p, b_cas1, S1, nullptr, nullptr, nullptr, none, 0, 1);
    // 5. off2 = lrelu(conv(cas_a)) -> S3   (TH=2)
    conv_mfma<true, false, 0, 4, 1, 2><<<gf, blk, 0, stream>>>(
        S1, nullptr, w_cas2p, b_cas2, S3, nullptr, nullptr, nullptr, none, 0, 1);

    // 6. pack2: om2 = conv(off2); feat3 = lrelu(mdcn(feat2, om2)) -> S1
    if (big) {
        Ptr4 slots{omA0, omA1, omB0, omB1};
        ompack(S3, w_om2p, b_om2, slots, 4);
        mdcn_mfma<1><<<dim3(10, 180, 4), blk, 0, stream>>>(S2, slots, w_dcn2p, b_dcn2, S1);
    } else {
        Ptr4 slots{omA0, omA1, nullptr, nullptr};
        for (int pp = 0; pp < 2; ++pp) {
            ompack(S3 + 2 * pp * CHW, w_om2p, b_om2, slots, 2);
            mdcn_mfma<1><<<dim3(10, 180, 2), blk, 0, stream>>>(S2 + 2 * pp * CHW, slots,
                                                               w_dcn2p, b_dcn2, S1 + 2 * pp * CHW);
        }
    }

    // 7. corr = dot(conv(ref,ta1)+b, conv(feat3,ta2)+b) -> S3  (fused, TH=2)
    tacorr_mfma<<<gt, blk, 0, stream>>>(S0, S1, w_ta1p, b_ta1, w_ta2p, b_ta2, corrf);

    // relocate ff weights out of d_out before the final conv overwrites it
    hipMemcpyAsync(ffw, w_ffp, 36864 * 2, hipMemcpyDeviceToDevice, stream);

    // 8. out = lrelu(conv(ref_t*corr, ff)) + ref  (f32 NCHW into d_out, TH=2)
    conv_mfma<true, true, 2, 4, 1, 2><<<gf, blk, 0, stream>>>(
        S0, nullptr, ffw, b_ff, nullptr, corrf, ref, (float*)d_out, none, 0, 1);
}

// Round 16
// 1104.602 us; speedup vs baseline: 1.0303x; 1.0303x over previous
//
#include <hip/hip_runtime.h>
#include <cmath>

// fusion_36455682409119 FINAL (= round-14 best, 1107us, 7.9x vs baseline):
//  - All convs: bf16 MFMA implicit GEMM, NHWC, XOR-swizzled LDS (0 bank conflicts),
//    XCD-aware bijective block swizzle, TH=2 feature tiles (4 blk/CU, 88% grid fill),
//    CIN=128 as two sequential 64-ch halves, om convs TH=4 + LDS-transpose
//    planar line stores, ta1+ta2+corr fused into one kernel.
//  - mdcn: CLOSED at vector-request-rate roofline (66.4M irreducible 16B gather
//    lines @ 1 req/cyc/CU = 193us; measured == model within 1%).
//  - r15 lesson: padding om chunk-3 to NM=4 (z=16 merge) costs more than the
//    launch tail it removes -> reverted to the NM=4 + NM=2 split.

using short8 = __attribute__((ext_vector_type(8))) short;
using f32x4  = __attribute__((ext_vector_type(4))) float;
using f32x2  = __attribute__((ext_vector_type(2))) float;

#define DEVINL static __device__ __forceinline__

DEVINL unsigned short f2bf(float f){
    unsigned u = __float_as_uint(f);
    u += 0x7fffu + ((u >> 16) & 1u);
    return (unsigned short)(u >> 16);
}
DEVINL unsigned pack2(float a, float b){ return (unsigned)f2bf(a) | ((unsigned)f2bf(b) << 16); }
DEVINL float bflo(unsigned u){ return __uint_as_float(u << 16); }
DEVINL float bfhi(unsigned u){ return __uint_as_float(u & 0xffff0000u); }
DEVINL float bf2f(unsigned short u){ return __uint_as_float((unsigned)u << 16); }
DEVINL float lrelu_f(float v){ return v >= 0.f ? v : 0.1f * v; }
DEVINL f32x2 up2(unsigned u){
    return f32x2{__uint_as_float(u << 16), __uint_as_float(u & 0xffff0000u)};
}

// m204 bijective XCD swizzle
DEVINL void swz_decode(int& bx, int& by, int& bz){
    const int gx = gridDim.x, gy = gridDim.y;
    int lin = blockIdx.x + gx * (blockIdx.y + gy * blockIdx.z);
    int nwg = gx * gy * gridDim.z;
    int q = nwg >> 3, r = nwg & 7;
    int xcd = lin & 7, idx = lin >> 3;
    int swz = (xcd < r ? xcd * (q + 1) : r + xcd * q) + idx;
    bz = swz / (gx * gy);
    int rem = swz - bz * gx * gy;
    by = rem / gx; bx = rem - by * gx;
}

struct Ptr4 { unsigned short* p[4]; };

// ---------------- both NCHW f32 -> NHWC bf16 transposes in one launch ----------------
__global__ __launch_bounds__(256) void nchw2nhwc2(const float* __restrict__ inA,
                                                  const float* __restrict__ inB,
                                                  unsigned short* __restrict__ outA,
                                                  unsigned short* __restrict__ outB)
{
    constexpr int HW = 180 * 320;
    const int blk = blockIdx.x;
    const float* in = (blk < 900) ? inA : inB;
    unsigned short* out = (blk < 900) ? outA : outB;
    size_t idx = (size_t)(blk % 900) * 256 + threadIdx.x;
    size_t bb = idx / HW, p = idx % HW;
    const float* src = in + (bb * 64) * (size_t)HW + p;
    unsigned short* dst = out + idx * 64;
    #pragma unroll
    for (int c0 = 0; c0 < 64; c0 += 16) {
        unsigned r[8];
        #pragma unroll
        for (int q = 0; q < 8; ++q)
            r[q] = pack2(src[(size_t)(c0 + 2*q) * HW], src[(size_t)(c0 + 2*q + 1) * HW]);
        *(uint4*)(dst + c0)     = *(uint4*)&r[0];
        *(uint4*)(dst + c0 + 8) = *(uint4*)&r[4];
    }
}

// ---------------- all weight prepacks in one launch ----------------
// kind 0: conv order [ch][j][cs][64oc][32k], k=c.
// kind 1: mdcn GROUP-major [s(18)][64oc][32k], k_lin = (g*9+tap)*8+c
struct PrepArgs {
    const float* src[11];
    unsigned short* dst[11];
    int cout[11]; int cin[11]; int nch[11]; int kind[11];
};

__global__ __launch_bounds__(256) void prep_all(PrepArgs a)
{
    const int t = blockIdx.y;
    const int idx = blockIdx.x * 256 + threadIdx.x;
    if (a.kind[t] == 1) {
        if (idx >= 36864) return;
        int kk = idx & 31, oc = (idx >> 5) & 63, s = idx >> 11;
        int k = s * 32 + kk;
        int gt = k >> 3, c8 = k & 7;
        int g = gt / 9, tp = gt - g * 9;
        a.dst[t][idx] = f2bf(a.src[t][((size_t)oc * 64 + g * 8 + c8) * 9 + tp]);
    } else {
        int cin = a.cin[t], cout = a.cout[t];
        int ncs = cin / 32;
        int total = a.nch[t] * 9 * ncs * 2048;
        if (idx >= total) return;
        int kk = idx & 31, oc_l = (idx >> 5) & 63, rest = idx >> 11;
        int cs = rest % ncs; int rest2 = rest / ncs;
        int j = rest2 % 9; int ch = rest2 / 9;
        int oc = ch * 64 + oc_l, c = cs * 32 + kk;
        float v = (oc < cout) ? a.src[t][((size_t)oc * cin + c) * 9 + j] : 0.f;
        a.dst[t][idx] = f2bf(v);
    }
}

// ---------------- MFMA conv 3x3 SAME, 64oc-chunk x (TH rows x 64px), HALVES passes ----
// TH=4: wave=row, 4 n-frags/wave (om path). TH=2: wave=(row,xhalf), 2 frags.
// OUTMODE 0: bf16 NHWC. 1: bf16 PLANAR via omout.p[b] (TH=4 only). 2: f32 NCHW +res.
template<bool ACT, bool SCALE, int OUTMODE, int NM, int HALVES, int TH>
__global__ __launch_bounds__(256, (TH == 2 ? 4 : 3)) void conv_mfma(
    const unsigned short* __restrict__ in0, const unsigned short* __restrict__ in1,
    const unsigned short* __restrict__ wgt, const float* __restrict__ bias,
    unsigned short* __restrict__ out, const float* __restrict__ corr,
    const float* __restrict__ res, float* __restrict__ outf,
    Ptr4 omout, int choff, int zdiv)
{
    constexpr int H = 180, W = 320, HW = H * W;
    constexpr int XW = 66;
    constexpr int HR = TH + 2;
    constexpr int NE = HR * XW * 8;
    constexpr int NFW = (TH == 4) ? 4 : 2;
    __shared__ __align__(16) unsigned char lds[HR * XW * 64 * 2];

    const int tid = threadIdx.x;
    int bx, by, bz;
    swz_decode(bx, by, bz);
    int b, ch;
    if (OUTMODE == 1) { b = bz / zdiv; ch = bz % zdiv + choff; }
    else              { b = bz; ch = 0; }
    const int x0 = bx * 64, y0 = by * TH;

    const int wv = tid >> 6, lane = tid & 63;
    const int ll = lane & 15, lh = lane >> 4;
    const int row_w = (TH == 4) ? wv : (wv & 1);
    const int nf0   = (TH == 4) ? 0  : ((wv >> 1) * 2);
    const unsigned short* wchunk = wgt + (size_t)ch * (9 * 2 * 2048);
    const int alane = ll * 32 + lh * 8;

    f32x4 acc[NM][NFW];
    #pragma unroll
    for (int mi = 0; mi < NM; ++mi)
        #pragma unroll
        for (int nf = 0; nf < NFW; ++nf) acc[mi][nf] = f32x4{0.f, 0.f, 0.f, 0.f};

    #pragma unroll
    for (int h = 0; h < HALVES; ++h) {
        if (h) __syncthreads();
        const unsigned short* srcb = (HALVES == 2 && h == 1) ? in1 : in0;
        for (int t = tid; t < NE; t += 256) {
            int cb = t & 7; int r = t >> 3;
            int xp = r % XW, yp = r / XW;
            int gx = x0 - 1 + xp, gy = y0 - 1 + yp;
            uint4 v = make_uint4(0, 0, 0, 0);
            if (gx >= 0 && gx < W && gy >= 0 && gy < H) {
                size_t pix = (size_t)b * HW + (size_t)gy * W + gx;
                v = *(const uint4*)(srcb + pix * 64 + cb * 8);
                if (SCALE) {
                    float cv = corr[pix];
                    v.x = pack2(bflo(v.x) * cv, bfhi(v.x) * cv);
                    v.y = pack2(bflo(v.y) * cv, bfhi(v.y) * cv);
                    v.z = pack2(bflo(v.z) * cv, bfhi(v.z) * cv);
                    v.w = pack2(bflo(v.w) * cv, bfhi(v.w) * cv);
                }
            }
            int blk = cb ^ (xp & 7);
            *(uint4*)&lds[(size_t)((yp * XW + xp) * 8 + blk) * 16] = v;
        }
        __syncthreads();

        #pragma unroll
        for (int j = 0; j < 9; ++j) {
            const int jy = j / 3, jx = j % 3;
            #pragma unroll
            for (int csl = 0; csl < 2; ++csl) {
                const int ws = j * (2 * HALVES) + h * 2 + csl;
                short8 a[NM];
                #pragma unroll
                for (int mi = 0; mi < NM; ++mi)
                    a[mi] = *(const short8*)(wchunk + (size_t)ws * 2048 + mi * 512 + alane);
                short8 bf[NFW];
                #pragma unroll
                for (int nfl = 0; nfl < NFW; ++nfl) {
                    int xp = (nf0 + nfl) * 16 + ll + jx;
                    int blk = (csl * 4 + lh) ^ (xp & 7);
                    int addr = (((row_w + jy) * XW + xp) * 8 + blk) * 16;
                    bf[nfl] = *(const short8*)&lds[addr];
                }
                #pragma unroll
                for (int mi = 0; mi < NM; ++mi)
                    #pragma unroll
                    for (int nfl = 0; nfl < NFW; ++nfl)
                        acc[mi][nfl] = __builtin_amdgcn_mfma_f32_16x16x32_bf16(a[mi], bf[nfl], acc[mi][nfl], 0, 0, 0);
            }
        }
    }

    const int py = y0 + row_w;
    const size_t pixrow = (size_t)b * HW + (size_t)py * W;

    if (OUTMODE == 1) {
        if constexpr (TH == 4) {
            // transpose via LDS (stride 72 px, 2B): full 128B-line planar stores
            __syncthreads();
            unsigned short* t2 = (unsigned short*)lds;
            #pragma unroll
            for (int nfl = 0; nfl < NFW; ++nfl) {
                const int px = nfl * 16 + ll;
                #pragma unroll
                for (int mi = 0; mi < NM; ++mi) {
                    #pragma unroll
                    for (int jj = 0; jj < 4; ++jj) {
                        int oc = mi * 16 + lh * 4 + jj;
                        int ocg = ch * 64 + oc;
                        if (ocg < 216) {
                            float t = acc[mi][nfl][jj] + bias[ocg];
                            t2[(size_t)(wv * 64 + oc) * 72 + px] = f2bf(ACT ? lrelu_f(t) : t);
                        }
                    }
                }
            }
            __syncthreads();
            unsigned short* oslot = omout.p[b];
            #pragma unroll
            for (int i = 0; i < 8; ++i) {
                int gu = i * 32 + (tid >> 3), q = tid & 7;
                int row = gu >> 6, oc = gu & 63;
                int ocg = ch * 64 + oc;
                if (oc < NM * 16 && ocg < 216) {
                    uint4 v = *(uint4*)&t2[(size_t)(row * 64 + oc) * 72 + q * 8];
                    *(uint4*)&oslot[(size_t)ocg * HW + (size_t)(y0 + row) * W + x0 + q * 8] = v;
                }
            }
        }
        return;
    }

    #pragma unroll
    for (int nfl = 0; nfl < NFW; ++nfl) {
        const int px = x0 + (nf0 + nfl) * 16 + ll;
        #pragma unroll
        for (int mi = 0; mi < NM; ++mi) {
            const int oc_l = mi * 16 + lh * 4;
            if (OUTMODE == 0) {
                float v[4];
                #pragma unroll
                for (int jj = 0; jj < 4; ++jj) {
                    float t = acc[mi][nfl][jj] + bias[oc_l + jj];
                    v[jj] = ACT ? lrelu_f(t) : t;
                }
                uint2 st; st.x = pack2(v[0], v[1]); st.y = pack2(v[2], v[3]);
                *(uint2*)&out[(pixrow + px) * 64 + oc_l] = st;
            } else {
                #pragma unroll
                for (int jj = 0; jj < 4; ++jj) {
                    int oc = oc_l + jj;
                    float t = acc[mi][nfl][jj] + bias[oc];
                    if (ACT) t = lrelu_f(t);
                    size_t idx = ((size_t)b * 64 + oc) * HW + (size_t)py * W + px;
                    outf[idx] = t + res[idx];
                }
            }
        }
    }
}

// ---------------- fused ta1+ta2+corr (r12/r14 proven, TH=4) ----------------
__global__ __launch_bounds__(256, 3) void tacorr_mfma(
    const unsigned short* __restrict__ inR,
    const unsigned short* __restrict__ inE,
    const unsigned short* __restrict__ wR, const float* __restrict__ bR,
    const unsigned short* __restrict__ wE, const float* __restrict__ bE,
    float* __restrict__ outf)
{
    constexpr int H = 180, W = 320, HW = H * W;
    constexpr int NE1 = 6 * 34 * 8;
    __shared__ __align__(16) unsigned char lds[2][6 * 34 * 64 * 2];

    const int tid = threadIdx.x;
    int bx, by, bz;
    swz_decode(bx, by, bz);
    const int b = bz;
    const int x0 = bx * 32, y0 = by * 4;

    for (int t = tid; t < 2 * NE1; t += 256) {
        int half = t / NE1, e = t - half * NE1;
        int cb = e & 7; int r = e >> 3;
        int xp = r % 34, yp = r / 34;
        int gx = x0 - 1 + xp, gy = y0 - 1 + yp;
        uint4 v = make_uint4(0, 0, 0, 0);
        if (gx >= 0 && gx < W && gy >= 0 && gy < H) {
            size_t pix = (size_t)b * HW + (size_t)gy * W + gx;
            const unsigned short* src = (half ? inE : inR) + pix * 64 + cb * 8;
            v = *(const uint4*)src;
        }
        int blk = cb ^ (xp & 7);
        *(uint4*)&lds[half][(size_t)((yp * 34 + xp) * 8 + blk) * 16] = v;
    }
    __syncthreads();

    const int wv = tid >> 6, lane = tid & 63;
    const int ll = lane & 15, lh = lane >> 4;
    const int alane = ll * 32 + lh * 8;

    f32x4 accR[4][2], accE[4][2];
    #pragma unroll
    for (int mi = 0; mi < 4; ++mi)
        #pragma unroll
        for (int nf = 0; nf < 2; ++nf) { accR[mi][nf] = f32x4{0,0,0,0}; accE[mi][nf] = f32x4{0,0,0,0}; }

    #pragma unroll
    for (int j = 0; j < 9; ++j) {
        const int jy = j / 3, jx = j % 3;
        #pragma unroll
        for (int cs = 0; cs < 2; ++cs) {
            const int s = j * 2 + cs;
            short8 aR[4], aE[4];
            #pragma unroll
            for (int mi = 0; mi < 4; ++mi) {
                aR[mi] = *(const short8*)(wR + (size_t)s * 2048 + mi * 512 + alane);
                aE[mi] = *(const short8*)(wE + (size_t)s * 2048 + mi * 512 + alane);
            }
            #pragma unroll
            for (int nf = 0; nf < 2; ++nf) {
                int xp = nf * 16 + ll + jx;
                int blk = (cs * 4 + lh) ^ (xp & 7);
                int addr = (((wv + jy) * 34 + xp) * 8 + blk) * 16;
                short8 bfR = *(const short8*)&lds[0][addr];
                short8 bfE = *(const short8*)&lds[1][addr];
                #pragma unroll
                for (int mi = 0; mi < 4; ++mi) {
                    accR[mi][nf] = __builtin_amdgcn_mfma_f32_16x16x32_bf16(aR[mi], bfR, accR[mi][nf], 0, 0, 0);
                    accE[mi][nf] = __builtin_amdgcn_mfma_f32_16x16x32_bf16(aE[mi], bfE, accE[mi][nf], 0, 0, 0);
                }
            }
        }
    }

    const int py = y0 + wv;
    const size_t pixrow = (size_t)b * HW + (size_t)py * W;
    #pragma unroll
    for (int nf = 0; nf < 2; ++nf) {
        const int px = x0 + nf * 16 + ll;
        float dot = 0.f;
        #pragma unroll
        for (int mi = 0; mi < 4; ++mi) {
            const int oc_l = mi * 16 + lh * 4;
            #pragma unroll
            for (int jj = 0; jj < 4; ++jj)
                dot += (accR[mi][nf][jj] + bR[oc_l + jj]) * (accE[mi][nf][jj] + bE[oc_l + jj]);
        }
        dot += __shfl_xor(dot, 16);
        dot += __shfl_xor(dot, 32);
        if (lh == 0) outf[pixrow + px] = dot;
    }
}

// ---------------- mdcn (request-rate roofline): group-major, single-phase ----------------
template<int ACT>
__global__ __launch_bounds__(256, 4) void mdcn_mfma(
    const unsigned short* __restrict__ x, Ptr4 omslots,
    const unsigned short* __restrict__ wgt, const float* __restrict__ bias,
    unsigned short* __restrict__ out)
{
    constexpr int H = 180, W = 320, HW = H * W;
    constexpr size_t CHW = (size_t)HW * 64;
    __shared__ __align__(16) unsigned char sv[72 * 32 * 16];

    const int tid = threadIdx.x;
    int bx, by, bz;
    swz_decode(bx, by, bz);
    const unsigned short* xb  = x + (size_t)bz * CHW;
    const unsigned short* omb = omslots.p[bz];
    unsigned short* ob        = out + (size_t)bz * CHW;
    const int px0 = bx * 32;
    const int py  = by;

    {
        const int pxl = tid & 31, g = tid >> 5;
        const int px = px0 + pxl;
        const size_t p = (size_t)py * W + px;
        const unsigned short* omg = omb + (size_t)(g * 9) * HW + p;

        float oyv[9], oxv[9], mmv[9];
        #pragma unroll
        for (int k = 0; k < 9; ++k) oyv[k] = bf2f(omg[(size_t)k * HW]);
        #pragma unroll
        for (int k = 0; k < 9; ++k) oxv[k] = bf2f(omg[(size_t)(72 + k) * HW]);
        #pragma unroll
        for (int k = 0; k < 9; ++k) mmv[k] = bf2f(omg[(size_t)(144 + k) * HW]);

        #pragma unroll
        for (int k = 0; k < 9; ++k) {
            float m = 1.f / (1.f + __expf(-mmv[k]));
            float pyf = (float)(py + (k / 3) - 1) + oyv[k];
            float pxf = (float)(px + (k % 3) - 1) + oxv[k];
            float y0f = floorf(pyf), x0f = floorf(pxf);
            float wy = pyf - y0f, wx = pxf - x0f;
            int yi = (int)y0f, xi = (int)x0f;
            bool vy0 = (yi >= 0) && (yi < H);
            bool vy1 = (yi + 1 >= 0) && (yi + 1 < H);
            bool vx0 = (xi >= 0) && (xi < W);
            bool vx1 = (xi + 1 >= 0) && (xi + 1 < W);
            float w00 = (vy0 && vx0) ? (1.f - wy) * (1.f - wx) * m : 0.f;
            float w01 = (vy0 && vx1) ? (1.f - wy) * wx * m : 0.f;
            float w10 = (vy1 && vx0) ? wy * (1.f - wx) * m : 0.f;
            float w11 = (vy1 && vx1) ? wy * wx * m : 0.f;
            int yc0 = min(max(yi, 0), H - 1), yc1 = min(max(yi + 1, 0), H - 1);
            int xc0 = min(max(xi, 0), W - 1), xc1 = min(max(xi + 1, 0), W - 1);
            uint4 c00 = *(const uint4*)(xb + ((size_t)(yc0 * W + xc0) * 64 + g * 8));
            uint4 c01 = *(const uint4*)(xb + ((size_t)(yc0 * W + xc1) * 64 + g * 8));
            uint4 c10 = *(const uint4*)(xb + ((size_t)(yc1 * W + xc0) * 64 + g * 8));
            uint4 c11 = *(const uint4*)(xb + ((size_t)(yc1 * W + xc1) * 64 + g * 8));
            const unsigned* p00 = (const unsigned*)&c00;
            const unsigned* p01 = (const unsigned*)&c01;
            const unsigned* p10 = (const unsigned*)&c10;
            const unsigned* p11 = (const unsigned*)&c11;
            unsigned r[4];
            #pragma unroll
            for (int q = 0; q < 4; ++q) {
                f32x2 rv = up2(p00[q]) * w00 + up2(p01[q]) * w01
                         + up2(p10[q]) * w10 + up2(p11[q]) * w11;
                r[q] = pack2(rv[0], rv[1]);
            }
            *(uint4*)&sv[(size_t)((g * 9 + k) * 32 + pxl) * 16] = *(uint4*)r;
        }
    }
    __syncthreads();

    const int wv = tid >> 6, lane = tid & 63;
    const int ll = lane & 15, lh = lane >> 4;
    f32x4 acc[2] = {f32x4{0.f,0.f,0.f,0.f}, f32x4{0.f,0.f,0.f,0.f}};
    #pragma unroll
    for (int s = 0; s < 18; ++s) {
        short8 a = *(const short8*)(wgt + (size_t)(s * 64 + wv * 16 + ll) * 32 + lh * 8);
        #pragma unroll
        for (int nf = 0; nf < 2; ++nf) {
            short8 bb = *(const short8*)&sv[(size_t)s * 2048 + lh * 512 + (nf * 16 + ll) * 16];
            acc[nf] = __builtin_amdgcn_mfma_f32_16x16x32_bf16(a, bb, acc[nf], 0, 0, 0);
        }
    }
    #pragma unroll
    for (int nf = 0; nf < 2; ++nf) {
        int opx = px0 + nf * 16 + ll;
        int oc0 = wv * 16 + lh * 4;
        float v[4];
        #pragma unroll
        for (int jj = 0; jj < 4; ++jj) {
            float t = acc[nf][jj] + bias[oc0 + jj];
            v[jj] = ACT ? lrelu_f(t) : t;
        }
        uint2 st; st.x = pack2(v[0], v[1]); st.y = pack2(v[2], v[3]);
        *(uint2*)&ob[((size_t)py * W + opx) * 64 + oc0] = st;
    }
}

extern "C" void kernel_launch(void* const* d_in, const int* in_sizes, int n_in,
                              void* d_out, int out_size, void* d_ws, size_t ws_size,
                              hipStream_t stream)
{
    const float* ref    = (const float*)d_in[0];
    const float* neb    = (const float*)d_in[1];
    const float* w_oc1  = (const float*)d_in[2];  const float* b_oc1  = (const float*)d_in[3];
    const float* w_om1  = (const float*)d_in[4];  const float* b_om1  = (const float*)d_in[5];
    const float* w_dcn1 = (const float*)d_in[6];  const float* b_dcn1 = (const float*)d_in[7];
    const float* w_fc   = (const float*)d_in[8];  const float* b_fc   = (const float*)d_in[9];
    const float* w_cas1 = (const float*)d_in[10]; const float* b_cas1 = (const float*)d_in[11];
    const float* w_cas2 = (const float*)d_in[12]; const float* b_cas2 = (const float*)d_in[13];
    const float* w_om2  = (const float*)d_in[14]; const float* b_om2  = (const float*)d_in[15];
    const float* w_dcn2 = (const float*)d_in[16]; const float* b_dcn2 = (const float*)d_in[17];
    const float* w_ta1  = (const float*)d_in[18]; const float* b_ta1  = (const float*)d_in[19];
    const float* w_ta2  = (const float*)d_in[20]; const float* b_ta2  = (const float*)d_in[21];
    const float* w_ff   = (const float*)d_in[22]; const float* b_ff   = (const float*)d_in[23];

    constexpr int H = 180, W = 320, HW = H * W;
    constexpr size_t CHW = (size_t)HW * 64;
    constexpr size_t SLB = 4 * CHW * 2;
    constexpr size_t OMSLOT_EL = (size_t)HW * 216;
    constexpr size_t OMSLOT_B  = OMSLOT_EL * 2;

    char* wsb = (char*)d_ws;
    unsigned short* S0 = (unsigned short*)(wsb);
    unsigned short* S1 = (unsigned short*)(wsb + SLB);
    unsigned short* S2 = (unsigned short*)(wsb + 2 * SLB);
    unsigned short* S3 = (unsigned short*)(wsb + 3 * SLB);
    float* corrf = (float*)S3;
    unsigned short* ffw = (unsigned short*)(wsb + SLB + (2u << 20));

    char* doutb = (char*)d_out;
    unsigned short* omA0 = (unsigned short*)doutb;
    unsigned short* omA1 = omA0 + OMSLOT_EL;
    unsigned short* wb   = (unsigned short*)(doutb + 2 * OMSLOT_B);
    const bool big = ws_size >= 4 * SLB + 2 * OMSLOT_B;
    unsigned short* omB0 = (unsigned short*)(wsb + 4 * SLB);
    unsigned short* omB1 = omB0 + OMSLOT_EL;

    unsigned short* w_oc1p = wb + 0;
    unsigned short* w_om1p = wb + 73728;
    unsigned short* w_dcn1p= wb + 221184;
    unsigned short* w_fcp  = wb + 258048;
    unsigned short* w_cas1p= wb + 294912;
    unsigned short* w_cas2p= wb + 368640;
    unsigned short* w_om2p = wb + 405504;
    unsigned short* w_dcn2p= wb + 552960;
    unsigned short* w_ta1p = wb + 589824;
    unsigned short* w_ta2p = wb + 626688;
    unsigned short* w_ffp  = wb + 663552;

    dim3 blk(256);
    dim3 gf(5, 90, 4);        // feature convs: TH=2, 1800 blocks
    dim3 g2(10, 45, 4);       // tacorr grid (32px, TH=4)
    Ptr4 none{};

    nchw2nhwc2<<<1800, blk, 0, stream>>>(ref, neb, S0, S1);

    {
        PrepArgs pa;
        const float* srcs[11] = {w_oc1, w_om1, w_dcn1, w_fc, w_cas1, w_cas2, w_om2, w_dcn2, w_ta1, w_ta2, w_ff};
        unsigned short* dsts[11] = {w_oc1p, w_om1p, w_dcn1p, w_fcp, w_cas1p, w_cas2p, w_om2p, w_dcn2p, w_ta1p, w_ta2p, w_ffp};
        int couts[11] = {64, 216, 0, 64, 64, 64, 216, 0, 64, 64, 64};
        int cins[11]  = {128, 64, 0, 64, 128, 64, 64, 0, 64, 64, 64};
        int nchs[11]  = {1, 4, 0, 1, 1, 1, 4, 0, 1, 1, 1};
        int kinds[11] = {0, 0, 1, 0, 0, 0, 0, 1, 0, 0, 0};
        for (int i = 0; i < 11; ++i) {
            pa.src[i] = srcs[i]; pa.dst[i] = dsts[i];
            pa.cout[i] = couts[i]; pa.cin[i] = cins[i]; pa.nch[i] = nchs[i]; pa.kind[i] = kinds[i];
        }
        prep_all<<<dim3(576, 11), blk, 0, stream>>>(pa);
    }

    // 1. off1 = lrelu(conv(concat(neb,ref))) -> S2   (two-half staging, TH=2)
    conv_mfma<true, false, 0, 4, 2, 2><<<gf, blk, 0, stream>>>(
        S1, S0, w_oc1p, b_oc1, S2, nullptr, nullptr, nullptr, none, 0, 1);

    // om conv: chunks 0-2 (NM=4) + chunk 3 tail (NM=2), TH=4 (transpose epilogue)
    auto ompack = [&](const unsigned short* inp, const unsigned short* wp, const float* bp,
                      Ptr4 slots, int nb){
        conv_mfma<false, false, 1, 4, 1, 4><<<dim3(5, 45, 3 * nb), blk, 0, stream>>>(
            inp, nullptr, wp, bp, nullptr, nullptr, nullptr, nullptr, slots, 0, 3);
        conv_mfma<false, false, 1, 2, 1, 4><<<dim3(5, 45, nb), blk, 0, stream>>>(
            inp, nullptr, wp, bp, nullptr, nullptr, nullptr, nullptr, slots, 3, 1);
    };

    // 2. pack1: om1 = conv(off1) [planar]; feat1 = mdcn(neb_t, om1) -> S3
    if (big) {
        Ptr4 slots{omA0, omA1, omB0, omB1};
        ompack(S2, w_om1p, b_om1, slots, 4);
        mdcn_mfma<0><<<dim3(10, 180, 4), blk, 0, stream>>>(S1, slots, w_dcn1p, b_dcn1, S3);
    } else {
        Ptr4 slots{omA0, omA1, nullptr, nullptr};
        for (int pp = 0; pp < 2; ++pp) {
            ompack(S2 + 2 * pp * CHW, w_om1p, b_om1, slots, 2);
            mdcn_mfma<0><<<dim3(10, 180, 2), blk, 0, stream>>>(S1 + 2 * pp * CHW, slots,
                                                               w_dcn1p, b_dcn1, S3 + 2 * pp * CHW);
        }
    }

    // 3. feat2 = lrelu(conv(feat1)) -> S2   (TH=2)
    conv_mfma<true, false, 0, 4, 1, 2><<<gf, blk, 0, stream>>>(
        S3, nullptr, w_fcp, b_fc, S2, nullptr, nullptr, nullptr, none, 0, 1);
    // 4. cas_a = lrelu(conv(concat(feat2,ref))) -> S1   (two-half, TH=2)
    conv_mfma<true, false, 0, 4, 2, 2><<<gf, blk, 0, stream>>>(
        S2, S0, w_cas1p, b_cas1, S1, nullptr, nullptr, nullptr, none, 0, 1);
    // 5. off2 = lrelu(conv(cas_a)) -> S3   (TH=2)
    conv_mfma<true, false, 0, 4, 1, 2><<<gf, blk, 0, stream>>>(
        S1, nullptr, w_cas2p, b_cas2, S3, nullptr, nullptr, nullptr, none, 0, 1);

    // 6. pack2: om2 = conv(off2); feat3 = lrelu(mdcn(feat2, om2)) -> S1
    if (big) {
        Ptr4 slots{omA0, omA1, omB0, omB1};
        ompack(S3, w_om2p, b_om2, slots, 4);
        mdcn_mfma<1><<<dim3(10, 180, 4), blk, 0, stream>>>(S2, slots, w_dcn2p, b_dcn2, S1);
    } else {
        Ptr4 slots{omA0, omA1, nullptr, nullptr};
        for (int pp = 0; pp < 2; ++pp) {
            ompack(S3 + 2 * pp * CHW, w_om2p, b_om2, slots, 2);
            mdcn_mfma<1><<<dim3(10, 180, 2), blk, 0, stream>>>(S2 + 2 * pp * CHW, slots,
                                                               w_dcn2p, b_dcn2, S1 + 2 * pp * CHW);
        }
    }

    // 7. corr = dot(conv(ref,ta1)+b, conv(feat3,ta2)+b) -> S3  (fully fused)
    tacorr_mfma<<<g2, blk, 0, stream>>>(S0, S1, w_ta1p, b_ta1, w_ta2p, b_ta2, corrf);

    // relocate ff weights out of d_out before the final conv overwrites it
    hipMemcpyAsync(ffw, w_ffp, 36864 * 2, hipMemcpyDeviceToDevice, stream);

    // 8. out = lrelu(conv(ref_t*corr, ff)) + ref  (f32 NCHW into d_out, TH=2)
    conv_mfma<true, true, 2, 4, 1, 2><<<gf, blk, 0, stream>>>(
        S0, nullptr, ffw, b_ff, nullptr, corrf, ref, (float*)d_out, none, 0, 1);
}